// Round 1
// baseline (135.468 us; speedup 1.0000x reference)
//
#include <hip/hip_runtime.h>

// Depth-4 path signature, D=6. Chunked Chen recursion + fused combine tree.
//
// R6 (this round): bet = dispatch-count overhead dominates (94.5us measured vs
// ~12us of arithmetic GPU work; no user kernel cracked the top-5 dispatches).
//  (1) 4 dispatches -> 2: whole combine tree is ONE kernel (64 blocks x 1024
//      threads; 4 sub-combiners of 256 lanes each + LDS merge; last-block-done
//      atomic flag runs the final 64->1 level and writes d_out).
//  (2) sig_chunk: P=4096 (4 waves/SIMD), LDS holds precomputed INCREMENTS
//      (kills 6 subs/step), vi/vj read per-lane from LDS (kills 10 cndmask),
//      unroll x2 over zero-padded rows (zero increment == identity step).
//
// State layout (floats), padded stride 1600 (16B-aligned):
//   L4 [0,1296)  L3 [1296,1512)  L2 [1512,1548)  L1 [1548,1554)
// Final output uses reference layout: L1[0,6) L2[6,42) L3[42,258) L4[258,1554).
#define SIGSZ 1554
#define PSTRIDE 1600
#define OFF4 0
#define OFF3 1296
#define OFF2 1512
#define OFF1 1548
#define VROWS 64     // LDS increment-row capacity; chunk_len <= VROWS-3
#define PMAX 4096

__device__ __forceinline__ float sel6(int idx, float a0, float a1, float a2,
                                      float a3, float a4, float a5) {
  float r = a0;
  r = (idx == 1) ? a1 : r;
  r = (idx == 2) ? a2 : r;
  r = (idx == 3) ? a3 : r;
  r = (idx == 4) ? a4 : r;
  r = (idx == 5) ? a5 : r;
  return r;
}

// ---------------------------------------------------------------------------
// Phase 1: one 64-thread block per chunk; lane p<36 owns (i,j)=(p/6,p%6).
//   S4[ijkl] += G*v_l,  G   = (vi*vj/24 + S1[i]*vj/6 + S2[ij]/2)*vk + S3[ijk]
//   S3[ijk]  += G2*vk,  G2  =  vi*vj/6  + S1[i]*vj/2 + S2[ij]
//   S2[ij]   += (vi/2 + S1[i])*vj ;  S1[i] += vi      (old values on RHS)
// LDS stores increments v_r = x[r+1]-x[r]; rows [steps, steps+3) zeroed so
// the x2-unrolled loop needs no clamps (v=0 is an identity step).
// ---------------------------------------------------------------------------
#define DECL4ROW(k) float s4_##k##_0 = 0.f, s4_##k##_1 = 0.f, s4_##k##_2 = 0.f, \
                          s4_##k##_3 = 0.f, s4_##k##_4 = 0.f, s4_##k##_5 = 0.f;

#define LOADROW(S, row) { \
  const float2* q_ = (const float2*)(vs + (row) * 6); \
  const float2 a_ = q_[0], b_ = q_[1], d_ = q_[2]; \
  S##v0 = a_.x; S##v1 = a_.y; S##v2 = b_.x; \
  S##v3 = b_.y; S##v4 = d_.x; S##v5 = d_.y; \
  S##vi = vs[(row) * 6 + i]; S##vj = vs[(row) * 6 + j]; \
}

#define MKG_S(S, k) const float G##S##k = fmaf(in4, S##v##k, s3_##k); \
                    s3_##k = fmaf(G2, S##v##k, s3_##k);
#define UPD_S(S, k, l) s4_##k##_##l = fmaf(G##S##k, S##v##l, s4_##k##_##l);
#define UPDROW_S(S, k) UPD_S(S,k,0) UPD_S(S,k,1) UPD_S(S,k,2) \
                       UPD_S(S,k,3) UPD_S(S,k,4) UPD_S(S,k,5)

#define STEP(S) { \
  const float aa = S##vi * S##vj; \
  const float sv = s1i * S##vj; \
  const float G2 = fmaf(aa, 1.f / 6.f, fmaf(sv, 0.5f, s2)); \
  const float in4 = fmaf(aa, 1.f / 24.f, fmaf(sv, 1.f / 6.f, s2 * 0.5f)); \
  MKG_S(S,0) MKG_S(S,1) MKG_S(S,2) MKG_S(S,3) MKG_S(S,4) MKG_S(S,5) \
  UPDROW_S(S,0) UPDROW_S(S,1) UPDROW_S(S,2) \
  UPDROW_S(S,3) UPDROW_S(S,4) UPDROW_S(S,5) \
  s2 = fmaf(fmaf(S##vi, 0.5f, s1i), S##vj, s2); \
  s1i += S##vi; \
}

__global__ __launch_bounds__(64, 4) void sig_chunk(const float* __restrict__ x,
                                                   float* __restrict__ out,
                                                   unsigned* __restrict__ counter,
                                                   int n_inc, int chunk_len) {
  __shared__ alignas(16) float vs[VROWS * 6];
  const int c = blockIdx.x;
  const int p = threadIdx.x;
  if (c == 0 && p == 0) *counter = 0u;   // re-armed every launch/replay
  const int t0 = c * chunk_len;
  int t1 = t0 + chunk_len; if (t1 > n_inc) t1 = n_inc;
  const int steps = (t1 > t0) ? (t1 - t0) : 0;
  const int pc = (p < 36) ? p : 35;
  const int i = pc / 6, j = pc % 6;
  const bool act = (p < 36);

  // ---- stage increments v_r = x[t0+r+1] - x[t0+r]; zero-pad 3 rows ----
  const int nv = steps * 6;
  const float* xb = x + (size_t)t0 * 6;
  for (int idx = p; idx < nv; idx += 64) vs[idx] = xb[idx + 6] - xb[idx];
  for (int idx = nv + p; idx < nv + 18; idx += 64) vs[idx] = 0.f;
  __syncthreads();

  DECL4ROW(0) DECL4ROW(1) DECL4ROW(2) DECL4ROW(3) DECL4ROW(4) DECL4ROW(5)
  float s3_0 = 0.f, s3_1 = 0.f, s3_2 = 0.f, s3_3 = 0.f, s3_4 = 0.f, s3_5 = 0.f;
  float s1i = 0.f, s2 = 0.f;

  float Av0, Av1, Av2, Av3, Av4, Av5, Avi, Avj;
  float Bv0, Bv1, Bv2, Bv3, Bv4, Bv5, Bvi, Bvj;
  LOADROW(A, 0)
  LOADROW(B, 1)
  const int steps_up = (steps + 1) & ~1;
  for (int r = 0; r < steps_up; r += 2) {
    STEP(A)
    LOADROW(A, r + 2)
    STEP(B)
    LOADROW(B, r + 3)
  }

  float* st = out + (size_t)c * PSTRIDE;
  if (act) {
    float4* o4 = (float4*)(st + OFF4 + pc * 36);
    float4 w;
    w.x = s4_0_0; w.y = s4_0_1; w.z = s4_0_2; w.w = s4_0_3; o4[0] = w;
    w.x = s4_0_4; w.y = s4_0_5; w.z = s4_1_0; w.w = s4_1_1; o4[1] = w;
    w.x = s4_1_2; w.y = s4_1_3; w.z = s4_1_4; w.w = s4_1_5; o4[2] = w;
    w.x = s4_2_0; w.y = s4_2_1; w.z = s4_2_2; w.w = s4_2_3; o4[3] = w;
    w.x = s4_2_4; w.y = s4_2_5; w.z = s4_3_0; w.w = s4_3_1; o4[4] = w;
    w.x = s4_3_2; w.y = s4_3_3; w.z = s4_3_4; w.w = s4_3_5; o4[5] = w;
    w.x = s4_4_0; w.y = s4_4_1; w.z = s4_4_2; w.w = s4_4_3; o4[6] = w;
    w.x = s4_4_4; w.y = s4_4_5; w.z = s4_5_0; w.w = s4_5_1; o4[7] = w;
    w.x = s4_5_2; w.y = s4_5_3; w.z = s4_5_4; w.w = s4_5_5; o4[8] = w;
    st[OFF3 + pc * 6 + 0] = s3_0;
    st[OFF3 + pc * 6 + 1] = s3_1;
    st[OFF3 + pc * 6 + 2] = s3_2;
    st[OFF3 + pc * 6 + 3] = s3_3;
    st[OFF3 + pc * 6 + 4] = s3_4;
    st[OFF3 + pc * 6 + 5] = s3_5;
    st[OFF2 + pc] = s2;
    if (j == 0) st[OFF1 + i] = s1i;
  }
}

// ---------------------------------------------------------------------------
// Phase 2 (single launch): 1024-thread blocks = 4 independent 256-lane
// sub-combiners (lane t<216 of each owns (i,j,k)). Each sub-combiner serially
// multiplies 16 states (ping-pong global prefetch, proven loop), sub-blocks
// 1..3 stage partials to LDS, sub-block 0 folds them in (assoc. of Chen).
// Block partial -> mid[]; threadfence + atomic counter; last block repeats
// the same structure over the <=64 block partials and writes final out.
// Zero state (all levels 0, implicit level-0 = 1) is the group identity, so
// clamped/empty spans need no special cases.
//   C4[ijk,l] = A4 + B4[ijk,l] + A1[i]B3[jk,l] + A2[ij]B2[k,l] + A3[ijk]B1[l]
//   C3[ijk]   = A3 + B3[ijk] + A1[i]B2[jk] + A2[ij]B1[k]
//   C2[ij]    = A2 + B2[ij] + A1[i]B1[j] ;  C1 = A1 + B1   (old A on RHS)
// ---------------------------------------------------------------------------
struct Acc {
  float a4_0, a4_1, a4_2, a4_3, a4_4, a4_5;
  float a3, a2;
  float a1_0, a1_1, a1_2, a1_3, a1_4, a1_5;
};

struct Lane {
  int i_, j_, k_, ij, tc;
  int oB4, oB3r, oB2r, oB2ij, oB2jk, oB3ijk, oB1k, oB1j;
  bool act;
};

__device__ __forceinline__ Lane make_lane(int pl) {
  Lane L;
  const int tc = (pl < 216) ? pl : 215;
  L.tc = tc; L.act = (pl < 216);
  L.k_ = tc % 6; L.ij = tc / 6; L.j_ = L.ij % 6; L.i_ = L.ij / 6;
  L.oB4 = OFF4 + tc * 6;
  L.oB3r = OFF3 + (L.j_ * 6 + L.k_) * 6;
  L.oB2r = OFF2 + L.k_ * 6;
  L.oB2ij = OFF2 + L.ij;
  L.oB2jk = OFF2 + L.j_ * 6 + L.k_;
  L.oB3ijk = OFF3 + tc;
  L.oB1k = OFF1 + L.k_;
  L.oB1j = OFF1 + L.j_;
  return L;
}

#define DECLSET(S)                                                  \
  float S##b4_0, S##b4_1, S##b4_2, S##b4_3, S##b4_4, S##b4_5;       \
  float S##b3r_0, S##b3r_1, S##b3r_2, S##b3r_3, S##b3r_4, S##b3r_5; \
  float S##b2r_0, S##b2r_1, S##b2r_2, S##b2r_3, S##b2r_4, S##b2r_5; \
  float S##b1_0, S##b1_1, S##b1_2, S##b1_3, S##b1_4, S##b1_5;       \
  float S##b2ij, S##b2jk, S##b3ijk, S##b1k, S##b1j;

#define LOADSET(S, bp) {                                            \
  const float2* q4 = (const float2*)((bp) + L.oB4);                 \
  const float2 u0 = q4[0], u1 = q4[1], u2 = q4[2];                  \
  S##b4_0 = u0.x; S##b4_1 = u0.y; S##b4_2 = u1.x;                   \
  S##b4_3 = u1.y; S##b4_4 = u2.x; S##b4_5 = u2.y;                   \
  const float2* q3 = (const float2*)((bp) + L.oB3r);                \
  const float2 w0 = q3[0], w1 = q3[1], w2 = q3[2];                  \
  S##b3r_0 = w0.x; S##b3r_1 = w0.y; S##b3r_2 = w1.x;                \
  S##b3r_3 = w1.y; S##b3r_4 = w2.x; S##b3r_5 = w2.y;                \
  const float2* q2 = (const float2*)((bp) + L.oB2r);                \
  const float2 y0 = q2[0], y1 = q2[1], y2 = q2[2];                  \
  S##b2r_0 = y0.x; S##b2r_1 = y0.y; S##b2r_2 = y1.x;                \
  S##b2r_3 = y1.y; S##b2r_4 = y2.x; S##b2r_5 = y2.y;                \
  const float2* q1 = (const float2*)((bp) + OFF1);                  \
  const float2 z0 = q1[0], z1 = q1[1], z2 = q1[2];                  \
  S##b1_0 = z0.x; S##b1_1 = z0.y; S##b1_2 = z1.x;                   \
  S##b1_3 = z1.y; S##b1_4 = z2.x; S##b1_5 = z2.y;                   \
  S##b2ij = (bp)[L.oB2ij]; S##b2jk = (bp)[L.oB2jk];                 \
  S##b3ijk = (bp)[L.oB3ijk];                                        \
  S##b1k = (bp)[L.oB1k]; S##b1j = (bp)[L.oB1j];                     \
}

#define PROD(S) {                                                   \
  const float a1i = sel6(L.i_, acc.a1_0, acc.a1_1, acc.a1_2,        \
                         acc.a1_3, acc.a1_4, acc.a1_5);             \
  acc.a4_0 = fmaf(acc.a3, S##b1_0, fmaf(acc.a2, S##b2r_0,           \
             fmaf(a1i, S##b3r_0, acc.a4_0 + S##b4_0)));             \
  acc.a4_1 = fmaf(acc.a3, S##b1_1, fmaf(acc.a2, S##b2r_1,           \
             fmaf(a1i, S##b3r_1, acc.a4_1 + S##b4_1)));             \
  acc.a4_2 = fmaf(acc.a3, S##b1_2, fmaf(acc.a2, S##b2r_2,           \
             fmaf(a1i, S##b3r_2, acc.a4_2 + S##b4_2)));             \
  acc.a4_3 = fmaf(acc.a3, S##b1_3, fmaf(acc.a2, S##b2r_3,           \
             fmaf(a1i, S##b3r_3, acc.a4_3 + S##b4_3)));             \
  acc.a4_4 = fmaf(acc.a3, S##b1_4, fmaf(acc.a2, S##b2r_4,           \
             fmaf(a1i, S##b3r_4, acc.a4_4 + S##b4_4)));             \
  acc.a4_5 = fmaf(acc.a3, S##b1_5, fmaf(acc.a2, S##b2r_5,           \
             fmaf(a1i, S##b3r_5, acc.a4_5 + S##b4_5)));             \
  acc.a3 = fmaf(acc.a2, S##b1k, fmaf(a1i, S##b2jk, acc.a3 + S##b3ijk)); \
  acc.a2 = fmaf(a1i, S##b1j, acc.a2 + S##b2ij);                     \
  acc.a1_0 += S##b1_0; acc.a1_1 += S##b1_1; acc.a1_2 += S##b1_2;    \
  acc.a1_3 += S##b1_3; acc.a1_4 += S##b1_4; acc.a1_5 += S##b1_5;    \
}

// product of states [first, first+cnt) left-to-right; cnt<=0 -> identity (0)
__device__ __forceinline__ Acc combine_span(const float* base, int first,
                                            int cnt, const Lane& L) {
  Acc acc = {};
  if (cnt <= 0) return acc;
  const float* sp0 = base + (size_t)first * PSTRIDE;
  {
    const float2* q4 = (const float2*)(sp0 + L.oB4);
    const float2 u0 = q4[0], u1 = q4[1], u2 = q4[2];
    acc.a4_0 = u0.x; acc.a4_1 = u0.y; acc.a4_2 = u1.x;
    acc.a4_3 = u1.y; acc.a4_4 = u2.x; acc.a4_5 = u2.y;
    acc.a3 = sp0[L.oB3ijk];
    acc.a2 = sp0[L.oB2ij];
    const float2* q1 = (const float2*)(sp0 + OFF1);
    const float2 z0 = q1[0], z1 = q1[1], z2 = q1[2];
    acc.a1_0 = z0.x; acc.a1_1 = z0.y; acc.a1_2 = z1.x;
    acc.a1_3 = z1.y; acc.a1_4 = z2.x; acc.a1_5 = z2.y;
  }
  if (cnt == 1) return acc;
  DECLSET(X)
  DECLSET(Y)
  const int end = first + cnt;
  int s = first + 1;
  {
    LOADSET(X, base + (size_t)s * PSTRIDE)
    const int sb = (s + 1 < end) ? (s + 1) : (end - 1);
    LOADSET(Y, base + (size_t)sb * PSTRIDE)
  }
  while (s + 1 < end) {
    PROD(X)
    {
      const int sn = (s + 2 < end) ? (s + 2) : (end - 1);
      LOADSET(X, base + (size_t)sn * PSTRIDE)
    }
    PROD(Y)
    {
      const int sn = (s + 3 < end) ? (s + 3) : (end - 1);
      LOADSET(Y, base + (size_t)sn * PSTRIDE)
    }
    s += 2;
  }
  if (s < end) { PROD(X) }
  return acc;
}

__device__ __forceinline__ void apply_state(Acc& acc, const float* bp,
                                            const Lane& L) {
  DECLSET(Z)
  LOADSET(Z, bp)
  PROD(Z)
}

__device__ __forceinline__ void store_partial(float* st, const Acc& acc,
                                              const Lane& L, int pl) {
  if (L.act) {
    float2* o2 = (float2*)(st + L.oB4);
    float2 w;
    w.x = acc.a4_0; w.y = acc.a4_1; o2[0] = w;
    w.x = acc.a4_2; w.y = acc.a4_3; o2[1] = w;
    w.x = acc.a4_4; w.y = acc.a4_5; o2[2] = w;
    st[L.oB3ijk] = acc.a3;
    if (L.k_ == 0) st[L.oB2ij] = acc.a2;
  }
  if (pl < 6)
    st[OFF1 + pl] = sel6(pl, acc.a1_0, acc.a1_1, acc.a1_2,
                         acc.a1_3, acc.a1_4, acc.a1_5);
}

__device__ __forceinline__ void store_final(float* o, const Acc& acc,
                                            const Lane& L, int pl) {
  // reference layout: L1 0, L2 6, L3 42, L4 258
  if (L.act) {
    float2* o2 = (float2*)(o + 258 + L.tc * 6);
    float2 w;
    w.x = acc.a4_0; w.y = acc.a4_1; o2[0] = w;
    w.x = acc.a4_2; w.y = acc.a4_3; o2[1] = w;
    w.x = acc.a4_4; w.y = acc.a4_5; o2[2] = w;
    o[42 + L.tc] = acc.a3;
    if (L.k_ == 0) o[6 + L.ij] = acc.a2;
  }
  if (pl < 6)
    o[pl] = sel6(pl, acc.a1_0, acc.a1_1, acc.a1_2,
                 acc.a1_3, acc.a1_4, acc.a1_5);
}

__global__ __launch_bounds__(1024) void sig_combine_all(
    const float* __restrict__ in, float* __restrict__ mid,
    float* __restrict__ out, unsigned* __restrict__ counter, int n_total) {
  __shared__ alignas(16) float lds[3 * PSTRIDE];
  __shared__ unsigned s_last;
  const int pl = threadIdx.x & 255;
  const int sub = threadIdx.x >> 8;
  const Lane L = make_lane(pl);

  // ---- level 1: this block folds states [b*64, b*64+64) from `in` ----
  {
    const int gs = blockIdx.x * 64 + sub * 16;
    int gc = n_total - gs; if (gc > 16) gc = 16;
    Acc acc = combine_span(in, gs, gc, L);
    if (sub != 0) store_partial(lds + (size_t)(sub - 1) * PSTRIDE, acc, L, pl);
    __syncthreads();
    if (sub == 0) {
      apply_state(acc, lds + 0 * PSTRIDE, L);
      apply_state(acc, lds + 1 * PSTRIDE, L);
      apply_state(acc, lds + 2 * PSTRIDE, L);
      store_partial(mid + (size_t)blockIdx.x * PSTRIDE, acc, L, pl);
    }
  }

  // ---- last-block-done flag (release fence -> atomic -> acquire fence) ----
  __threadfence();
  __syncthreads();
  if (threadIdx.x == 0)
    s_last = (atomicAdd(counter, 1u) == (unsigned)(gridDim.x - 1)) ? 1u : 0u;
  __syncthreads();
  if (!s_last) return;
  __threadfence();

  // ---- level 2: fold the gridDim.x block partials, write final output ----
  {
    const int gs = sub * 16;
    int gc = (int)gridDim.x - gs; if (gc > 16) gc = 16;
    Acc acc = combine_span(mid, gs, gc, L);
    __syncthreads();
    if (sub != 0) store_partial(lds + (size_t)(sub - 1) * PSTRIDE, acc, L, pl);
    __syncthreads();
    if (sub == 0) {
      apply_state(acc, lds + 0 * PSTRIDE, L);
      apply_state(acc, lds + 1 * PSTRIDE, L);
      apply_state(acc, lds + 2 * PSTRIDE, L);
      store_final(out, acc, L, pl);
    }
  }
}

extern "C" void kernel_launch(void* const* d_in, const int* in_sizes, int n_in,
                              void* d_out, int out_size, void* d_ws, size_t ws_size,
                              hipStream_t stream) {
  const float* x = (const float*)d_in[0];
  const int Lrows = in_sizes[0] / 6;
  const int n_inc = Lrows - 1;

  int P = PMAX;
  int chunk_len = (n_inc + P - 1) / P;
  if (chunk_len > VROWS - 3) {             // keep LDS increment staging in bounds
    chunk_len = VROWS - 3;
    P = (n_inc + chunk_len - 1) / chunk_len;
  }

  float* ws0 = (float*)d_ws;                               // PMAX chunk states
  float* ws1 = ws0 + (size_t)PMAX * PSTRIDE;               // <=64 block partials
  unsigned* counter = (unsigned*)(ws1 + (size_t)64 * PSTRIDE);

  sig_chunk<<<P, 64, 0, stream>>>(x, ws0, counter, n_inc, chunk_len);

  const int nb = (P + 63) / 64;            // <=64 blocks; last one finalizes
  sig_combine_all<<<nb, 1024, 0, stream>>>(ws0, ws1, (float*)d_out, counter, P);
}

// Round 2
// 127.393 us; speedup vs baseline: 1.0634x; 1.0634x over previous
//
#include <hip/hip_runtime.h>

// Depth-4 path signature, D=6. Chunked Chen recursion + fused combine tree.
//
// R7: R6's fused combine regressed (66us/dispatch) because 1024-thread blocks
// capped VGPR at 64 (compiler targeted 2 blocks/CU) while a combiner lane
// needs ~110 live floats -> scratch spill thrash (VALUBusy 1.8%, HBM 2.8%).
// Fix: 512-thread blocks (2 x 256-lane sub-combiners), __launch_bounds__(512,2)
// -> 256-VGPR cap, no spill. Tree: 64 blocks x (2 subs x 32-chain) -> 64
// partials; last-block-done folds them (2 subs x 32-chain). sig_chunk
// unchanged from R6 (increments in LDS, x2 unroll over zero-padded rows).
//
// State layout (floats), padded stride 1600 (16B-aligned):
//   L4 [0,1296)  L3 [1296,1512)  L2 [1512,1548)  L1 [1548,1554)
// Final output uses reference layout: L1[0,6) L2[6,42) L3[42,258) L4[258,1554).
#define SIGSZ 1554
#define PSTRIDE 1600
#define OFF4 0
#define OFF3 1296
#define OFF2 1512
#define OFF1 1548
#define VROWS 64     // LDS increment-row capacity; chunk_len <= VROWS-3
#define PMAX 4096

__device__ __forceinline__ float sel6(int idx, float a0, float a1, float a2,
                                      float a3, float a4, float a5) {
  float r = a0;
  r = (idx == 1) ? a1 : r;
  r = (idx == 2) ? a2 : r;
  r = (idx == 3) ? a3 : r;
  r = (idx == 4) ? a4 : r;
  r = (idx == 5) ? a5 : r;
  return r;
}

// ---------------------------------------------------------------------------
// Phase 1: one 64-thread block per chunk; lane p<36 owns (i,j)=(p/6,p%6).
//   S4[ijkl] += G*v_l,  G   = (vi*vj/24 + S1[i]*vj/6 + S2[ij]/2)*vk + S3[ijk]
//   S3[ijk]  += G2*vk,  G2  =  vi*vj/6  + S1[i]*vj/2 + S2[ij]
//   S2[ij]   += (vi/2 + S1[i])*vj ;  S1[i] += vi      (old values on RHS)
// LDS stores increments v_r = x[r+1]-x[r]; rows [steps, steps+3) zeroed so
// the x2-unrolled loop needs no clamps (v=0 is an identity step).
// ---------------------------------------------------------------------------
#define DECL4ROW(k) float s4_##k##_0 = 0.f, s4_##k##_1 = 0.f, s4_##k##_2 = 0.f, \
                          s4_##k##_3 = 0.f, s4_##k##_4 = 0.f, s4_##k##_5 = 0.f;

#define LOADROW(S, row) { \
  const float2* q_ = (const float2*)(vs + (row) * 6); \
  const float2 a_ = q_[0], b_ = q_[1], d_ = q_[2]; \
  S##v0 = a_.x; S##v1 = a_.y; S##v2 = b_.x; \
  S##v3 = b_.y; S##v4 = d_.x; S##v5 = d_.y; \
  S##vi = vs[(row) * 6 + i]; S##vj = vs[(row) * 6 + j]; \
}

#define MKG_S(S, k) const float G##S##k = fmaf(in4, S##v##k, s3_##k); \
                    s3_##k = fmaf(G2, S##v##k, s3_##k);
#define UPD_S(S, k, l) s4_##k##_##l = fmaf(G##S##k, S##v##l, s4_##k##_##l);
#define UPDROW_S(S, k) UPD_S(S,k,0) UPD_S(S,k,1) UPD_S(S,k,2) \
                       UPD_S(S,k,3) UPD_S(S,k,4) UPD_S(S,k,5)

#define STEP(S) { \
  const float aa = S##vi * S##vj; \
  const float sv = s1i * S##vj; \
  const float G2 = fmaf(aa, 1.f / 6.f, fmaf(sv, 0.5f, s2)); \
  const float in4 = fmaf(aa, 1.f / 24.f, fmaf(sv, 1.f / 6.f, s2 * 0.5f)); \
  MKG_S(S,0) MKG_S(S,1) MKG_S(S,2) MKG_S(S,3) MKG_S(S,4) MKG_S(S,5) \
  UPDROW_S(S,0) UPDROW_S(S,1) UPDROW_S(S,2) \
  UPDROW_S(S,3) UPDROW_S(S,4) UPDROW_S(S,5) \
  s2 = fmaf(fmaf(S##vi, 0.5f, s1i), S##vj, s2); \
  s1i += S##vi; \
}

__global__ __launch_bounds__(64, 4) void sig_chunk(const float* __restrict__ x,
                                                   float* __restrict__ out,
                                                   unsigned* __restrict__ counter,
                                                   int n_inc, int chunk_len) {
  __shared__ alignas(16) float vs[VROWS * 6];
  const int c = blockIdx.x;
  const int p = threadIdx.x;
  if (c == 0 && p == 0) *counter = 0u;   // re-armed every launch/replay
  const int t0 = c * chunk_len;
  int t1 = t0 + chunk_len; if (t1 > n_inc) t1 = n_inc;
  const int steps = (t1 > t0) ? (t1 - t0) : 0;
  const int pc = (p < 36) ? p : 35;
  const int i = pc / 6, j = pc % 6;
  const bool act = (p < 36);

  // ---- stage increments v_r = x[t0+r+1] - x[t0+r]; zero-pad 3 rows ----
  const int nv = steps * 6;
  const float* xb = x + (size_t)t0 * 6;
  for (int idx = p; idx < nv; idx += 64) vs[idx] = xb[idx + 6] - xb[idx];
  for (int idx = nv + p; idx < nv + 18; idx += 64) vs[idx] = 0.f;
  __syncthreads();

  DECL4ROW(0) DECL4ROW(1) DECL4ROW(2) DECL4ROW(3) DECL4ROW(4) DECL4ROW(5)
  float s3_0 = 0.f, s3_1 = 0.f, s3_2 = 0.f, s3_3 = 0.f, s3_4 = 0.f, s3_5 = 0.f;
  float s1i = 0.f, s2 = 0.f;

  float Av0, Av1, Av2, Av3, Av4, Av5, Avi, Avj;
  float Bv0, Bv1, Bv2, Bv3, Bv4, Bv5, Bvi, Bvj;
  LOADROW(A, 0)
  LOADROW(B, 1)
  const int steps_up = (steps + 1) & ~1;
  for (int r = 0; r < steps_up; r += 2) {
    STEP(A)
    LOADROW(A, r + 2)
    STEP(B)
    LOADROW(B, r + 3)
  }

  float* st = out + (size_t)c * PSTRIDE;
  if (act) {
    float4* o4 = (float4*)(st + OFF4 + pc * 36);
    float4 w;
    w.x = s4_0_0; w.y = s4_0_1; w.z = s4_0_2; w.w = s4_0_3; o4[0] = w;
    w.x = s4_0_4; w.y = s4_0_5; w.z = s4_1_0; w.w = s4_1_1; o4[1] = w;
    w.x = s4_1_2; w.y = s4_1_3; w.z = s4_1_4; w.w = s4_1_5; o4[2] = w;
    w.x = s4_2_0; w.y = s4_2_1; w.z = s4_2_2; w.w = s4_2_3; o4[3] = w;
    w.x = s4_2_4; w.y = s4_2_5; w.z = s4_3_0; w.w = s4_3_1; o4[4] = w;
    w.x = s4_3_2; w.y = s4_3_3; w.z = s4_3_4; w.w = s4_3_5; o4[5] = w;
    w.x = s4_4_0; w.y = s4_4_1; w.z = s4_4_2; w.w = s4_4_3; o4[6] = w;
    w.x = s4_4_4; w.y = s4_4_5; w.z = s4_5_0; w.w = s4_5_1; o4[7] = w;
    w.x = s4_5_2; w.y = s4_5_3; w.z = s4_5_4; w.w = s4_5_5; o4[8] = w;
    st[OFF3 + pc * 6 + 0] = s3_0;
    st[OFF3 + pc * 6 + 1] = s3_1;
    st[OFF3 + pc * 6 + 2] = s3_2;
    st[OFF3 + pc * 6 + 3] = s3_3;
    st[OFF3 + pc * 6 + 4] = s3_4;
    st[OFF3 + pc * 6 + 5] = s3_5;
    st[OFF2 + pc] = s2;
    if (j == 0) st[OFF1 + i] = s1i;
  }
}

// ---------------------------------------------------------------------------
// Phase 2 (single launch): 512-thread blocks = 2 independent 256-lane
// sub-combiners (lane t<216 owns (i,j,k)). Each sub serially multiplies 32
// states (ping-pong global prefetch); sub 1 stages its partial to LDS, sub 0
// folds it in (associativity of Chen product). Block partial -> mid[];
// threadfence + atomic counter; last block repeats over the <=64 block
// partials and writes the final output. Zero state is the group identity, so
// clamped/empty spans need no special cases.
//   C4[ijk,l] = A4 + B4[ijk,l] + A1[i]B3[jk,l] + A2[ij]B2[k,l] + A3[ijk]B1[l]
//   C3[ijk]   = A3 + B3[ijk] + A1[i]B2[jk] + A2[ij]B1[k]
//   C2[ij]    = A2 + B2[ij] + A1[i]B1[j] ;  C1 = A1 + B1   (old A on RHS)
// ---------------------------------------------------------------------------
struct Acc {
  float a4_0, a4_1, a4_2, a4_3, a4_4, a4_5;
  float a3, a2;
  float a1_0, a1_1, a1_2, a1_3, a1_4, a1_5;
};

struct Lane {
  int i_, j_, k_, ij, tc;
  int oB4, oB3r, oB2r, oB2ij, oB2jk, oB3ijk, oB1k, oB1j;
  bool act;
};

__device__ __forceinline__ Lane make_lane(int pl) {
  Lane L;
  const int tc = (pl < 216) ? pl : 215;
  L.tc = tc; L.act = (pl < 216);
  L.k_ = tc % 6; L.ij = tc / 6; L.j_ = L.ij % 6; L.i_ = L.ij / 6;
  L.oB4 = OFF4 + tc * 6;
  L.oB3r = OFF3 + (L.j_ * 6 + L.k_) * 6;
  L.oB2r = OFF2 + L.k_ * 6;
  L.oB2ij = OFF2 + L.ij;
  L.oB2jk = OFF2 + L.j_ * 6 + L.k_;
  L.oB3ijk = OFF3 + tc;
  L.oB1k = OFF1 + L.k_;
  L.oB1j = OFF1 + L.j_;
  return L;
}

#define DECLSET(S)                                                  \
  float S##b4_0, S##b4_1, S##b4_2, S##b4_3, S##b4_4, S##b4_5;       \
  float S##b3r_0, S##b3r_1, S##b3r_2, S##b3r_3, S##b3r_4, S##b3r_5; \
  float S##b2r_0, S##b2r_1, S##b2r_2, S##b2r_3, S##b2r_4, S##b2r_5; \
  float S##b1_0, S##b1_1, S##b1_2, S##b1_3, S##b1_4, S##b1_5;       \
  float S##b2ij, S##b2jk, S##b3ijk, S##b1k, S##b1j;

#define LOADSET(S, bp) {                                            \
  const float2* q4 = (const float2*)((bp) + L.oB4);                 \
  const float2 u0 = q4[0], u1 = q4[1], u2 = q4[2];                  \
  S##b4_0 = u0.x; S##b4_1 = u0.y; S##b4_2 = u1.x;                   \
  S##b4_3 = u1.y; S##b4_4 = u2.x; S##b4_5 = u2.y;                   \
  const float2* q3 = (const float2*)((bp) + L.oB3r);                \
  const float2 w0 = q3[0], w1 = q3[1], w2 = q3[2];                  \
  S##b3r_0 = w0.x; S##b3r_1 = w0.y; S##b3r_2 = w1.x;                \
  S##b3r_3 = w1.y; S##b3r_4 = w2.x; S##b3r_5 = w2.y;                \
  const float2* q2 = (const float2*)((bp) + L.oB2r);                \
  const float2 y0 = q2[0], y1 = q2[1], y2 = q2[2];                  \
  S##b2r_0 = y0.x; S##b2r_1 = y0.y; S##b2r_2 = y1.x;                \
  S##b2r_3 = y1.y; S##b2r_4 = y2.x; S##b2r_5 = y2.y;                \
  const float2* q1 = (const float2*)((bp) + OFF1);                  \
  const float2 z0 = q1[0], z1 = q1[1], z2 = q1[2];                  \
  S##b1_0 = z0.x; S##b1_1 = z0.y; S##b1_2 = z1.x;                   \
  S##b1_3 = z1.y; S##b1_4 = z2.x; S##b1_5 = z2.y;                   \
  S##b2ij = (bp)[L.oB2ij]; S##b2jk = (bp)[L.oB2jk];                 \
  S##b3ijk = (bp)[L.oB3ijk];                                        \
  S##b1k = (bp)[L.oB1k]; S##b1j = (bp)[L.oB1j];                     \
}

#define PROD(S) {                                                   \
  const float a1i = sel6(L.i_, acc.a1_0, acc.a1_1, acc.a1_2,        \
                         acc.a1_3, acc.a1_4, acc.a1_5);             \
  acc.a4_0 = fmaf(acc.a3, S##b1_0, fmaf(acc.a2, S##b2r_0,           \
             fmaf(a1i, S##b3r_0, acc.a4_0 + S##b4_0)));             \
  acc.a4_1 = fmaf(acc.a3, S##b1_1, fmaf(acc.a2, S##b2r_1,           \
             fmaf(a1i, S##b3r_1, acc.a4_1 + S##b4_1)));             \
  acc.a4_2 = fmaf(acc.a3, S##b1_2, fmaf(acc.a2, S##b2r_2,           \
             fmaf(a1i, S##b3r_2, acc.a4_2 + S##b4_2)));             \
  acc.a4_3 = fmaf(acc.a3, S##b1_3, fmaf(acc.a2, S##b2r_3,           \
             fmaf(a1i, S##b3r_3, acc.a4_3 + S##b4_3)));             \
  acc.a4_4 = fmaf(acc.a3, S##b1_4, fmaf(acc.a2, S##b2r_4,           \
             fmaf(a1i, S##b3r_4, acc.a4_4 + S##b4_4)));             \
  acc.a4_5 = fmaf(acc.a3, S##b1_5, fmaf(acc.a2, S##b2r_5,           \
             fmaf(a1i, S##b3r_5, acc.a4_5 + S##b4_5)));             \
  acc.a3 = fmaf(acc.a2, S##b1k, fmaf(a1i, S##b2jk, acc.a3 + S##b3ijk)); \
  acc.a2 = fmaf(a1i, S##b1j, acc.a2 + S##b2ij);                     \
  acc.a1_0 += S##b1_0; acc.a1_1 += S##b1_1; acc.a1_2 += S##b1_2;    \
  acc.a1_3 += S##b1_3; acc.a1_4 += S##b1_4; acc.a1_5 += S##b1_5;    \
}

// product of states [first, first+cnt) left-to-right; cnt<=0 -> identity (0)
__device__ __forceinline__ Acc combine_span(const float* base, int first,
                                            int cnt, const Lane& L) {
  Acc acc = {};
  if (cnt <= 0) return acc;
  const float* sp0 = base + (size_t)first * PSTRIDE;
  {
    const float2* q4 = (const float2*)(sp0 + L.oB4);
    const float2 u0 = q4[0], u1 = q4[1], u2 = q4[2];
    acc.a4_0 = u0.x; acc.a4_1 = u0.y; acc.a4_2 = u1.x;
    acc.a4_3 = u1.y; acc.a4_4 = u2.x; acc.a4_5 = u2.y;
    acc.a3 = sp0[L.oB3ijk];
    acc.a2 = sp0[L.oB2ij];
    const float2* q1 = (const float2*)(sp0 + OFF1);
    const float2 z0 = q1[0], z1 = q1[1], z2 = q1[2];
    acc.a1_0 = z0.x; acc.a1_1 = z0.y; acc.a1_2 = z1.x;
    acc.a1_3 = z1.y; acc.a1_4 = z2.x; acc.a1_5 = z2.y;
  }
  if (cnt == 1) return acc;
  DECLSET(X)
  DECLSET(Y)
  const int end = first + cnt;
  int s = first + 1;
  {
    LOADSET(X, base + (size_t)s * PSTRIDE)
    const int sb = (s + 1 < end) ? (s + 1) : (end - 1);
    LOADSET(Y, base + (size_t)sb * PSTRIDE)
  }
  while (s + 1 < end) {
    PROD(X)
    {
      const int sn = (s + 2 < end) ? (s + 2) : (end - 1);
      LOADSET(X, base + (size_t)sn * PSTRIDE)
    }
    PROD(Y)
    {
      const int sn = (s + 3 < end) ? (s + 3) : (end - 1);
      LOADSET(Y, base + (size_t)sn * PSTRIDE)
    }
    s += 2;
  }
  if (s < end) { PROD(X) }
  return acc;
}

__device__ __forceinline__ void apply_state(Acc& acc, const float* bp,
                                            const Lane& L) {
  DECLSET(Z)
  LOADSET(Z, bp)
  PROD(Z)
}

__device__ __forceinline__ void store_partial(float* st, const Acc& acc,
                                              const Lane& L, int pl) {
  if (L.act) {
    float2* o2 = (float2*)(st + L.oB4);
    float2 w;
    w.x = acc.a4_0; w.y = acc.a4_1; o2[0] = w;
    w.x = acc.a4_2; w.y = acc.a4_3; o2[1] = w;
    w.x = acc.a4_4; w.y = acc.a4_5; o2[2] = w;
    st[L.oB3ijk] = acc.a3;
    if (L.k_ == 0) st[L.oB2ij] = acc.a2;
  }
  if (pl < 6)
    st[OFF1 + pl] = sel6(pl, acc.a1_0, acc.a1_1, acc.a1_2,
                         acc.a1_3, acc.a1_4, acc.a1_5);
}

__device__ __forceinline__ void store_final(float* o, const Acc& acc,
                                            const Lane& L, int pl) {
  // reference layout: L1 0, L2 6, L3 42, L4 258
  if (L.act) {
    float2* o2 = (float2*)(o + 258 + L.tc * 6);
    float2 w;
    w.x = acc.a4_0; w.y = acc.a4_1; o2[0] = w;
    w.x = acc.a4_2; w.y = acc.a4_3; o2[1] = w;
    w.x = acc.a4_4; w.y = acc.a4_5; o2[2] = w;
    o[42 + L.tc] = acc.a3;
    if (L.k_ == 0) o[6 + L.ij] = acc.a2;
  }
  if (pl < 6)
    o[pl] = sel6(pl, acc.a1_0, acc.a1_1, acc.a1_2,
                 acc.a1_3, acc.a1_4, acc.a1_5);
}

__global__ __launch_bounds__(512, 2) void sig_combine_all(
    const float* __restrict__ in, float* __restrict__ mid,
    float* __restrict__ out, unsigned* __restrict__ counter, int n_total) {
  __shared__ alignas(16) float lds[PSTRIDE];
  __shared__ unsigned s_last;
  const int pl = threadIdx.x & 255;
  const int sub = threadIdx.x >> 8;   // 0 or 1
  const Lane L = make_lane(pl);

  // ---- level 1: this block folds states [b*64, b*64+64) from `in` ----
  {
    const int gs = blockIdx.x * 64 + sub * 32;
    int gc = n_total - gs; if (gc > 32) gc = 32;
    Acc acc = combine_span(in, gs, gc, L);
    if (sub != 0) store_partial(lds, acc, L, pl);
    __syncthreads();
    if (sub == 0) {
      apply_state(acc, lds, L);
      store_partial(mid + (size_t)blockIdx.x * PSTRIDE, acc, L, pl);
    }
  }

  // ---- last-block-done flag (release fence -> atomic -> acquire fence) ----
  __threadfence();
  __syncthreads();
  if (threadIdx.x == 0)
    s_last = (atomicAdd(counter, 1u) == (unsigned)(gridDim.x - 1)) ? 1u : 0u;
  __syncthreads();
  if (!s_last) return;
  __threadfence();

  // ---- level 2: fold the gridDim.x block partials, write final output ----
  {
    const int gs = sub * 32;
    int gc = (int)gridDim.x - gs; if (gc > 32) gc = 32;
    Acc acc = combine_span(mid, gs, gc, L);
    __syncthreads();
    if (sub != 0) store_partial(lds, acc, L, pl);
    __syncthreads();
    if (sub == 0) {
      apply_state(acc, lds, L);
      store_final(out, acc, L, pl);
    }
  }
}

extern "C" void kernel_launch(void* const* d_in, const int* in_sizes, int n_in,
                              void* d_out, int out_size, void* d_ws, size_t ws_size,
                              hipStream_t stream) {
  const float* x = (const float*)d_in[0];
  const int Lrows = in_sizes[0] / 6;
  const int n_inc = Lrows - 1;

  int P = PMAX;
  int chunk_len = (n_inc + P - 1) / P;
  if (chunk_len > VROWS - 3) {             // keep LDS increment staging in bounds
    chunk_len = VROWS - 3;
    P = (n_inc + chunk_len - 1) / chunk_len;
  }

  float* ws0 = (float*)d_ws;                               // PMAX chunk states
  float* ws1 = ws0 + (size_t)PMAX * PSTRIDE;               // <=64 block partials
  unsigned* counter = (unsigned*)(ws1 + (size_t)64 * PSTRIDE);

  sig_chunk<<<P, 64, 0, stream>>>(x, ws0, counter, n_inc, chunk_len);

  const int nb = (P + 63) / 64;            // <=64 blocks; last one finalizes
  sig_combine_all<<<nb, 512, 0, stream>>>(ws0, ws1, (float*)d_out, counter, P);
}

// Round 3
// 98.420 us; speedup vs baseline: 1.3764x; 1.2944x over previous
//
#include <hip/hip_runtime.h>

// Depth-4 path signature, D=6. Chunked Chen recursion + 3-level combine tree.
//
// R8: REVERT the fused combine (R6/R7: compiler sank the ping-pong prefetch
// -> serial load-latency chain, 55-67us). Back to R0's proven sig_combine
// (256 thr, launch_bounds(256,1) -> full VGPR budget, 16-chains, 3 dispatches).
// Timing model across R0-R2: dur ~= 42us poison-fill + sum(kernels) + ~28us
// fixed overhead -> only kernel-sum matters. This round's improvement: chunk
// step rewritten as float2 ext-vector fma (v_pk_fma_f32 on CDNA4) -> 36 L4
// FMAs -> 18 pk-FMAs (+L3/G packed too), ~70 -> ~45 issue slots/step.
// P=4096 (chunk_len=25, 4 waves/SIMD).
//
// State layout (floats), padded stride 1600 (16B-aligned):
//   L4 [0,1296)  L3 [1296,1512)  L2 [1512,1548)  L1 [1548,1554)
// Final output uses reference layout: L1[0,6) L2[6,42) L3[42,258) L4[258,1554).
#define SIGSZ 1554
#define PSTRIDE 1600
#define OFF4 0
#define OFF3 1296
#define OFF2 1512
#define OFF1 1548
#define VROWS 64     // LDS increment-row capacity; chunk_len <= VROWS-3
#define PMAX 4096

typedef float v2f __attribute__((ext_vector_type(2)));

__device__ __forceinline__ v2f vfma2(v2f a, v2f b, v2f c) {
  return __builtin_elementwise_fma(a, b, c);
}
__device__ __forceinline__ v2f splat2(float s) {
  v2f r; r.x = s; r.y = s; return r;
}

__device__ __forceinline__ float sel6(int idx, float a0, float a1, float a2,
                                      float a3, float a4, float a5) {
  float r = a0;
  r = (idx == 1) ? a1 : r;
  r = (idx == 2) ? a2 : r;
  r = (idx == 3) ? a3 : r;
  r = (idx == 4) ? a4 : r;
  r = (idx == 5) ? a5 : r;
  return r;
}

// ---------------------------------------------------------------------------
// Phase 1: one 64-thread block per chunk; lane p<36 owns (i,j)=(p/6,p%6).
//   S4[ijkl] += G*v_l,  G   = (vi*vj/24 + S1[i]*vj/6 + S2[ij]/2)*vk + S3[ijk]
//   S3[ijk]  += G2*vk,  G2  =  vi*vj/6  + S1[i]*vj/2 + S2[ij]
//   S2[ij]   += (vi/2 + S1[i])*vj ;  S1[i] += vi      (old values on RHS)
// LDS stores increments v_r = x[r+1]-x[r]; rows [steps, steps+3) zeroed so
// the x2-unrolled loop needs no clamps (v=0 is an identity step).
// All level-3/4 state held as float2 pairs -> v_pk_fma_f32.
// ---------------------------------------------------------------------------
#define DECL4ROW(k) v2f s4_##k##_0 = {0.f, 0.f}, s4_##k##_1 = {0.f, 0.f}, \
                        s4_##k##_2 = {0.f, 0.f};

#define LOADROW(S, row) { \
  const v2f* q_ = (const v2f*)(vs + (row) * 6); \
  S##p0 = q_[0]; S##p1 = q_[1]; S##p2 = q_[2]; \
  S##vi = vs[(row) * 6 + i]; S##vj = vs[(row) * 6 + j]; \
}

#define UPD4K(S, k, gk) { \
  const v2f gk2 = splat2(gk); \
  s4_##k##_0 = vfma2(gk2, S##p0, s4_##k##_0); \
  s4_##k##_1 = vfma2(gk2, S##p1, s4_##k##_1); \
  s4_##k##_2 = vfma2(gk2, S##p2, s4_##k##_2); \
}

#define STEP(S) { \
  const float aa = S##vi * S##vj; \
  const float sv = s1i * S##vj; \
  const float G2 = fmaf(aa, 1.f / 6.f, fmaf(sv, 0.5f, s2)); \
  const float in4 = fmaf(aa, 1.f / 24.f, fmaf(sv, 1.f / 6.f, s2 * 0.5f)); \
  const v2f in42 = splat2(in4), G22 = splat2(G2); \
  const v2f Gp0 = vfma2(in42, S##p0, s3p0); \
  const v2f Gp1 = vfma2(in42, S##p1, s3p1); \
  const v2f Gp2 = vfma2(in42, S##p2, s3p2); \
  s3p0 = vfma2(G22, S##p0, s3p0); \
  s3p1 = vfma2(G22, S##p1, s3p1); \
  s3p2 = vfma2(G22, S##p2, s3p2); \
  UPD4K(S, 0, Gp0.x) UPD4K(S, 1, Gp0.y) UPD4K(S, 2, Gp1.x) \
  UPD4K(S, 3, Gp1.y) UPD4K(S, 4, Gp2.x) UPD4K(S, 5, Gp2.y) \
  s2 = fmaf(fmaf(S##vi, 0.5f, s1i), S##vj, s2); \
  s1i += S##vi; \
}

__global__ __launch_bounds__(64, 4) void sig_chunk(const float* __restrict__ x,
                                                   float* __restrict__ out,
                                                   int n_inc, int chunk_len) {
  __shared__ alignas(16) float vs[VROWS * 6];
  const int c = blockIdx.x;
  const int p = threadIdx.x;
  const int t0 = c * chunk_len;
  int t1 = t0 + chunk_len; if (t1 > n_inc) t1 = n_inc;
  const int steps = (t1 > t0) ? (t1 - t0) : 0;
  const int pc = (p < 36) ? p : 35;
  const int i = pc / 6, j = pc % 6;
  const bool act = (p < 36);

  // ---- stage increments v_r = x[t0+r+1] - x[t0+r]; zero-pad 3 rows ----
  const int nv = steps * 6;
  const float* xb = x + (size_t)t0 * 6;
  for (int idx = p; idx < nv; idx += 64) vs[idx] = xb[idx + 6] - xb[idx];
  for (int idx = nv + p; idx < nv + 18; idx += 64) vs[idx] = 0.f;
  __syncthreads();

  DECL4ROW(0) DECL4ROW(1) DECL4ROW(2) DECL4ROW(3) DECL4ROW(4) DECL4ROW(5)
  v2f s3p0 = {0.f, 0.f}, s3p1 = {0.f, 0.f}, s3p2 = {0.f, 0.f};
  float s1i = 0.f, s2 = 0.f;

  v2f Ap0, Ap1, Ap2; float Avi, Avj;
  v2f Bp0, Bp1, Bp2; float Bvi, Bvj;
  LOADROW(A, 0)
  LOADROW(B, 1)
  const int steps_up = (steps + 1) & ~1;
  for (int r = 0; r < steps_up; r += 2) {
    STEP(A)
    LOADROW(A, r + 2)
    STEP(B)
    LOADROW(B, r + 3)
  }

  float* st = out + (size_t)c * PSTRIDE;
  if (act) {
    float4* o4 = (float4*)(st + OFF4 + pc * 36);
    float4 w;
    w.x = s4_0_0.x; w.y = s4_0_0.y; w.z = s4_0_1.x; w.w = s4_0_1.y; o4[0] = w;
    w.x = s4_0_2.x; w.y = s4_0_2.y; w.z = s4_1_0.x; w.w = s4_1_0.y; o4[1] = w;
    w.x = s4_1_1.x; w.y = s4_1_1.y; w.z = s4_1_2.x; w.w = s4_1_2.y; o4[2] = w;
    w.x = s4_2_0.x; w.y = s4_2_0.y; w.z = s4_2_1.x; w.w = s4_2_1.y; o4[3] = w;
    w.x = s4_2_2.x; w.y = s4_2_2.y; w.z = s4_3_0.x; w.w = s4_3_0.y; o4[4] = w;
    w.x = s4_3_1.x; w.y = s4_3_1.y; w.z = s4_3_2.x; w.w = s4_3_2.y; o4[5] = w;
    w.x = s4_4_0.x; w.y = s4_4_0.y; w.z = s4_4_1.x; w.w = s4_4_1.y; o4[6] = w;
    w.x = s4_4_2.x; w.y = s4_4_2.y; w.z = s4_5_0.x; w.w = s4_5_0.y; o4[7] = w;
    w.x = s4_5_1.x; w.y = s4_5_1.y; w.z = s4_5_2.x; w.w = s4_5_2.y; o4[8] = w;
    st[OFF3 + pc * 6 + 0] = s3p0.x;
    st[OFF3 + pc * 6 + 1] = s3p0.y;
    st[OFF3 + pc * 6 + 2] = s3p1.x;
    st[OFF3 + pc * 6 + 3] = s3p1.y;
    st[OFF3 + pc * 6 + 4] = s3p2.x;
    st[OFF3 + pc * 6 + 5] = s3p2.y;
    st[OFF2 + pc] = s2;
    if (j == 0) st[OFF1 + i] = s1i;
  }
}

// ---------------------------------------------------------------------------
// Phase 2 (R0-proven): combine `group` consecutive states left-to-right.
// 256-thread blocks; lane t<216 owns (i,j,k) = (t/36, (t/6)%6, t%6), keeping
// C4[ijk,:] (6), C3[ijk], and REDUNDANT copies of C2[ij], C1[:] in regs.
// Every lane fully independent: B-slices loaded global->named regs, ping-pong
// prefetched 2 products ahead. No LDS, no barriers.
//   C4[ijk,l] = A4 + B4[ijk,l] + A1[i]B3[jk,l] + A2[ij]B2[k,l] + A3[ijk]B1[l]
//   C3[ijk]   = A3 + B3[ijk] + A1[i]B2[jk] + A2[ij]B1[k]
//   C2[ij]    = A2 + B2[ij] + A1[i]B1[j] ;  C1 = A1 + B1   (old A on RHS)
// ---------------------------------------------------------------------------

// 31 named scalars per prefetch set
#define DECLSET(S)                                                  \
  float S##b4_0, S##b4_1, S##b4_2, S##b4_3, S##b4_4, S##b4_5;       \
  float S##b3r_0, S##b3r_1, S##b3r_2, S##b3r_3, S##b3r_4, S##b3r_5; \
  float S##b2r_0, S##b2r_1, S##b2r_2, S##b2r_3, S##b2r_4, S##b2r_5; \
  float S##b1_0, S##b1_1, S##b1_2, S##b1_3, S##b1_4, S##b1_5;       \
  float S##b2ij, S##b2jk, S##b3ijk, S##b1k, S##b1j;

#define LOADSET(S, bp) {                                            \
  const float2* q4 = (const float2*)((bp) + oB4);                   \
  float2 u0 = q4[0], u1 = q4[1], u2 = q4[2];                        \
  S##b4_0 = u0.x; S##b4_1 = u0.y; S##b4_2 = u1.x;                   \
  S##b4_3 = u1.y; S##b4_4 = u2.x; S##b4_5 = u2.y;                   \
  const float2* q3 = (const float2*)((bp) + oB3r);                  \
  float2 w0 = q3[0], w1 = q3[1], w2 = q3[2];                        \
  S##b3r_0 = w0.x; S##b3r_1 = w0.y; S##b3r_2 = w1.x;                \
  S##b3r_3 = w1.y; S##b3r_4 = w2.x; S##b3r_5 = w2.y;                \
  const float2* q2 = (const float2*)((bp) + oB2r);                  \
  float2 y0 = q2[0], y1 = q2[1], y2 = q2[2];                        \
  S##b2r_0 = y0.x; S##b2r_1 = y0.y; S##b2r_2 = y1.x;                \
  S##b2r_3 = y1.y; S##b2r_4 = y2.x; S##b2r_5 = y2.y;                \
  const float2* q1 = (const float2*)((bp) + OFF1);                  \
  float2 z0 = q1[0], z1 = q1[1], z2 = q1[2];                        \
  S##b1_0 = z0.x; S##b1_1 = z0.y; S##b1_2 = z1.x;                   \
  S##b1_3 = z1.y; S##b1_4 = z2.x; S##b1_5 = z2.y;                   \
  S##b2ij = (bp)[oB2ij]; S##b2jk = (bp)[oB2jk];                     \
  S##b3ijk = (bp)[oB3ijk];                                          \
  S##b1k = (bp)[oB1k]; S##b1j = (bp)[oB1j];                         \
}

#define PROD(S) {                                                   \
  const float a1i = sel6(i_, a1_0, a1_1, a1_2, a1_3, a1_4, a1_5);   \
  a4_0 = fmaf(a3, S##b1_0, fmaf(a2, S##b2r_0,                       \
         fmaf(a1i, S##b3r_0, a4_0 + S##b4_0)));                     \
  a4_1 = fmaf(a3, S##b1_1, fmaf(a2, S##b2r_1,                       \
         fmaf(a1i, S##b3r_1, a4_1 + S##b4_1)));                     \
  a4_2 = fmaf(a3, S##b1_2, fmaf(a2, S##b2r_2,                       \
         fmaf(a1i, S##b3r_2, a4_2 + S##b4_2)));                     \
  a4_3 = fmaf(a3, S##b1_3, fmaf(a2, S##b2r_3,                       \
         fmaf(a1i, S##b3r_3, a4_3 + S##b4_3)));                     \
  a4_4 = fmaf(a3, S##b1_4, fmaf(a2, S##b2r_4,                       \
         fmaf(a1i, S##b3r_4, a4_4 + S##b4_4)));                     \
  a4_5 = fmaf(a3, S##b1_5, fmaf(a2, S##b2r_5,                       \
         fmaf(a1i, S##b3r_5, a4_5 + S##b4_5)));                     \
  a3 = fmaf(a2, S##b1k, fmaf(a1i, S##b2jk, a3 + S##b3ijk));         \
  a2 = fmaf(a1i, S##b1j, a2 + S##b2ij);                             \
  a1_0 += S##b1_0; a1_1 += S##b1_1; a1_2 += S##b1_2;                \
  a1_3 += S##b1_3; a1_4 += S##b1_4; a1_5 += S##b1_5;                \
}

__global__ __launch_bounds__(256, 1) void sig_combine(const float* __restrict__ in,
                                                      float* __restrict__ out,
                                                      int n_total, int group,
                                                      int final_out) {
  const int b = blockIdx.x;
  const int p = threadIdx.x;
  const int start = b * group;
  int end = start + group; if (end > n_total) end = n_total;
  const int tc = (p < 216) ? p : 215;
  const bool act = (p < 216);
  const int k_ = tc % 6;
  const int ij = tc / 6;
  const int j_ = ij % 6;
  const int i_ = ij / 6;

  // loop-invariant element offsets
  const int oB4 = OFF4 + tc * 6;
  const int oB3r = OFF3 + (j_ * 6 + k_) * 6;
  const int oB2r = OFF2 + k_ * 6;
  const int oB2ij = OFF2 + ij;
  const int oB2jk = OFF2 + j_ * 6 + k_;
  const int oB3ijk = OFF3 + tc;
  const int oB1k = OFF1 + k_;
  const int oB1j = OFF1 + j_;

  // ---- init A from state `start` ----
  const float* sp0 = in + (size_t)start * PSTRIDE;
  float a4_0, a4_1, a4_2, a4_3, a4_4, a4_5;
  {
    const float2* q4 = (const float2*)(sp0 + oB4);
    float2 u0 = q4[0], u1 = q4[1], u2 = q4[2];
    a4_0 = u0.x; a4_1 = u0.y; a4_2 = u1.x;
    a4_3 = u1.y; a4_4 = u2.x; a4_5 = u2.y;
  }
  float a3 = sp0[oB3ijk];
  float a2 = sp0[oB2ij];
  float a1_0, a1_1, a1_2, a1_3, a1_4, a1_5;
  {
    const float2* q1 = (const float2*)(sp0 + OFF1);
    float2 z0 = q1[0], z1 = q1[1], z2 = q1[2];
    a1_0 = z0.x; a1_1 = z0.y; a1_2 = z1.x;
    a1_3 = z1.y; a1_4 = z2.x; a1_5 = z2.y;
  }

  DECLSET(A)
  DECLSET(B)

  int s = start + 1;
  {
    const int sa = (s < end) ? s : (end - 1);
    LOADSET(A, in + (size_t)sa * PSTRIDE)
    const int sb = (s + 1 < end) ? (s + 1) : (end - 1);
    LOADSET(B, in + (size_t)sb * PSTRIDE)
  }
  while (s + 1 < end) {
    PROD(A)
    {
      const int sn = (s + 2 < end) ? (s + 2) : (end - 1);
      LOADSET(A, in + (size_t)sn * PSTRIDE)
    }
    PROD(B)
    {
      const int sn = (s + 3 < end) ? (s + 3) : (end - 1);
      LOADSET(B, in + (size_t)sn * PSTRIDE)
    }
    s += 2;
  }
  if (s < end) { PROD(A) }

  const float a1p = sel6(p, a1_0, a1_1, a1_2, a1_3, a1_4, a1_5);
  if (final_out) {
    float* o = out;   // reference layout: L1 0, L2 6, L3 42, L4 258
    if (act) {
      float2* o2 = (float2*)(o + 258 + tc * 6);
      float2 w;
      w.x = a4_0; w.y = a4_1; o2[0] = w;
      w.x = a4_2; w.y = a4_3; o2[1] = w;
      w.x = a4_4; w.y = a4_5; o2[2] = w;
      o[42 + tc] = a3;
      if (k_ == 0) o[6 + ij] = a2;
    }
    if (p < 6) o[p] = a1p;
  } else {
    float* st = out + (size_t)b * PSTRIDE;
    if (act) {
      float2* o2 = (float2*)(st + oB4);
      float2 w;
      w.x = a4_0; w.y = a4_1; o2[0] = w;
      w.x = a4_2; w.y = a4_3; o2[1] = w;
      w.x = a4_4; w.y = a4_5; o2[2] = w;
      st[oB3ijk] = a3;
      if (k_ == 0) st[oB2ij] = a2;
    }
    if (p < 6) st[OFF1 + p] = a1p;
  }
}

extern "C" void kernel_launch(void* const* d_in, const int* in_sizes, int n_in,
                              void* d_out, int out_size, void* d_ws, size_t ws_size,
                              hipStream_t stream) {
  const float* x = (const float*)d_in[0];
  const int Lrows = in_sizes[0] / 6;
  const int n_inc = Lrows - 1;

  int P = PMAX;
  int chunk_len = (n_inc + P - 1) / P;
  if (chunk_len > VROWS - 3) {             // keep LDS increment staging in bounds
    chunk_len = VROWS - 3;
    P = (n_inc + chunk_len - 1) / chunk_len;
  }

  float* ws0 = (float*)d_ws;                               // P chunk states
  float* ws1 = ws0 + (size_t)PMAX * PSTRIDE;               // tree partials

  sig_chunk<<<P, 64, 0, stream>>>(x, ws0, n_inc, chunk_len);

  float* cur = ws0;
  float* other = ws1;
  int n = P;
  while (n > 1) {
    const int g = (n <= 16) ? n : 16;
    const int nb = (n + g - 1) / g;
    const int fin = (nb == 1);
    sig_combine<<<nb, 256, 0, stream>>>(cur, fin ? (float*)d_out : other, n, g, fin);
    float* t = cur; cur = other; other = t;
    n = nb;
  }
}